// Round 1
// baseline (525.300 us; speedup 1.0000x reference)
//
#include <hip/hip_runtime.h>
#include <hip/hip_bf16.h>

// Depthwise causal FIR conv along l.
// x: (b=8, l=4096, h=16, d=128) f32, contiguous => (b, l, C=2048) with C innermost.
// w: (h, d, 31) f32 => (C, 31).
// y[b,t,c] = sum_{j=0..30} w[c,j] * x[b, t-30+j, c]   (zero-padded for t-30+j < 0)

constexpr int K    = 31;
constexpr int C    = 2048;
constexpr int L    = 4096;
constexpr int B    = 8;
constexpr int LSEG = 256;   // time samples per block (multiple of 32)
constexpr int TPB  = 256;   // threads per block = channels per block

__global__ __launch_bounds__(TPB) void
_DepthwiseFIRConv1d_31877247271427_kernel(const float* __restrict__ x,
                                          const float* __restrict__ w,
                                          float* __restrict__ y) {
    const int c  = blockIdx.x * TPB + threadIdx.x;   // channel
    const int t0 = blockIdx.y * LSEG;                // segment start (multiple of 32)
    const int b  = blockIdx.z;

    const float* xp = x + (size_t)b * L * C + c;
    float*       yp = y + (size_t)b * L * C + c;

    // per-channel weights in registers
    float wt[K];
#pragma unroll
    for (int j = 0; j < K; ++j) wt[j] = w[c * K + j];

    // circular history buffer: xb[t & 31] == x[b, t, c]
    float xb[32];
    // preload history t0-31 .. t0-1 (xb[0] is written at u=0 before first use)
#pragma unroll
    for (int i = 1; i <= 31; ++i) {
        const int t = t0 - i;
        xb[t & 31] = (t >= 0) ? xp[(size_t)t * C] : 0.0f;
    }

    for (int i = 0; i < LSEG; i += 32) {
        const int tbase = t0 + i;   // multiple of 32 => (tbase+u) & 31 == u
#pragma unroll
        for (int u = 0; u < 32; ++u) {
            xb[u] = xp[(size_t)(tbase + u) * C];   // newest sample x[t]
            float acc = 0.0f;
            // x[t-30+j] lives at xb[(t + j + 2) & 31] = xb[(u + j + 2) & 31]
#pragma unroll
            for (int j = 0; j < K; ++j) {
                acc = fmaf(wt[j], xb[(u + j + 2) & 31], acc);
            }
            yp[(size_t)(tbase + u) * C] = acc;
        }
    }
}

extern "C" void kernel_launch(void* const* d_in, const int* in_sizes, int n_in,
                              void* d_out, int out_size, void* d_ws, size_t ws_size,
                              hipStream_t stream) {
    const float* x = (const float*)d_in[0];
    const float* w = (const float*)d_in[1];
    float*       y = (float*)d_out;

    dim3 grid(C / TPB, L / LSEG, B);   // (8, 16, 8) = 1024 blocks
    dim3 block(TPB);
    _DepthwiseFIRConv1d_31877247271427_kernel<<<grid, block, 0, stream>>>(x, w, y);
}

// Round 4
// 501.945 us; speedup vs baseline: 1.0465x; 1.0465x over previous
//
#include <hip/hip_runtime.h>
#include <hip/hip_bf16.h>

// Depthwise causal FIR conv along l.
// x: (b=8, l=4096, h=16, d=128) f32, contiguous => (b, l, C=2048) with C innermost.
// w: (h, d, 31) f32 => (C, 31).
// y[b,t,c] = sum_{j=0..30} w[c,j] * x[b, t-30+j, c]   (zero-padded for t-30+j < 0)

constexpr int K    = 31;
constexpr int C    = 2048;
constexpr int L    = 4096;
constexpr int B    = 8;
constexpr int LSEG = 128;   // time samples per block (multiple of 32)
constexpr int TPB  = 256;   // threads per block = channels per block

__global__ __launch_bounds__(TPB) void
_DepthwiseFIRConv1d_31877247271427_kernel(const float* __restrict__ x,
                                          const float* __restrict__ w,
                                          float* __restrict__ y) {
    const int c  = blockIdx.x * TPB + threadIdx.x;   // channel
    const int t0 = blockIdx.y * LSEG;                // segment start (multiple of 32)
    const int b  = blockIdx.z;

    const float* xp = x + (size_t)b * L * C + c;
    float*       yp = y + (size_t)b * L * C + c;

    // per-channel weights in registers
    float wt[K];
#pragma unroll
    for (int j = 0; j < K; ++j) wt[j] = w[c * K + j];

    // circular history buffer: xb[t & 31] == x[b, t, c]
    float xb[32];
    // preload history t0-31 .. t0-1 (xb[t0 & 31] is overwritten at u=0 before use)
#pragma unroll
    for (int i = 1; i <= 31; ++i) {
        const int t = t0 - i;
        xb[t & 31] = (t >= 0) ? xp[(size_t)t * C] : 0.0f;
    }

    for (int i = 0; i < LSEG; i += 32) {
        const int tbase = t0 + i;   // multiple of 32 => (tbase+u) & 31 == u
#pragma unroll
        for (int u = 0; u < 32; ++u) {
            xb[u] = xp[(size_t)(tbase + u) * C];   // newest sample x[t]
            float acc = 0.0f;
            // x[t-30+j] lives at xb[(t + j + 2) & 31] = xb[(u + j + 2) & 31]
#pragma unroll
            for (int j = 0; j < K; ++j) {
                acc = fmaf(wt[j], xb[(u + j + 2) & 31], acc);
            }
            yp[(size_t)(tbase + u) * C] = acc;
        }
    }
}

extern "C" void kernel_launch(void* const* d_in, const int* in_sizes, int n_in,
                              void* d_out, int out_size, void* d_ws, size_t ws_size,
                              hipStream_t stream) {
    const float* x = (const float*)d_in[0];
    const float* w = (const float*)d_in[1];
    float*       y = (float*)d_out;

    dim3 grid(C / TPB, L / LSEG, B);   // (8, 32, 8) = 2048 blocks
    dim3 block(TPB);
    _DepthwiseFIRConv1d_31877247271427_kernel<<<grid, block, 0, stream>>>(x, w, y);
}